// Round 2
// 1053.586 us; speedup vs baseline: 1.5306x; 1.5306x over previous
//
#include <hip/hip_runtime.h>

#define QINF 1000000000.0f
constexpr int B = 64;
constexpr int V = 8192;
constexpr int VP2 = V + 2;

constexpr int TIW = 16;              // i-rows per wave (MFMA N dim)
constexpr int WPB = 4;               // waves per block
constexpr int NSJ = 4;               // j strips (grid.y)
constexpr int KSTRIP = V / NSJ;      // 2048 j per wave
constexpr int JC = 64;               // j per chunk
constexpr int NCHUNK = KSTRIP / JC;  // 32
constexpr int CKB = 3 * TIW * JC * 2;  // 6144 B per-wave LDS: 48 rows x 128 B

using bf16x8 = __attribute__((ext_vector_type(8))) short;
using f32x4  = __attribute__((ext_vector_type(4))) float;

__device__ __forceinline__ unsigned f2bf2(float a, float b) {
    // RNE float->bf16 packed pair (finite inputs)
    unsigned ua = __builtin_bit_cast(unsigned, a);
    unsigned ub = __builtin_bit_cast(unsigned, b);
    ua += 0x7FFFu + ((ua >> 16) & 1u);
    ub += 0x7FFFu + ((ub >> 16) & 1u);
    return (ua >> 16) | (ub & 0xFFFF0000u);
}

__global__ __launch_bounds__(64) void mask_kernel(const float* __restrict__ func,
                                                  float* __restrict__ out) {
    int b = threadIdx.x;
    if (b < B) {
        float f1 = func[(size_t)b * VP2 + V];
        float f2 = func[(size_t)b * VP2 + V + 1];
        out[b * 3 + 0] = -QINF * f1;
        out[b * 3 + 1] = -QINF * (1.0f - (1.0f - f1) * (1.0f - f2));
        out[b * 3 + 2] = 0.0f;
    }
}

// Wave-autonomous streaming: no __syncthreads in the main loop. Each wave owns
// TIW i-rows and one j-strip; cooc chunk is register-double-buffered (issued in
// half-chunks to cap VGPR pressure), converted to bf16 into wave-PRIVATE
// swizzled LDS (same-wave DS is in-order -> no barrier), arg fragments are
// built straight from L2-resident global memory.
__global__ __launch_bounds__(256, 2) void cooc_kernel(const float* __restrict__ func,
                                                      const float* __restrict__ arg,
                                                      const float* __restrict__ cooc,
                                                      float* __restrict__ out) {
    __shared__ alignas(16) char ck_all[WPB * CKB];  // 24 KB
    __shared__ float red[WPB][B][3];                // 3 KB block-reduce buffer

    const int tid  = threadIdx.x;
    const int lane = tid & 63;
    const int w    = tid >> 6;
    const int il   = lane & 15;
    const int quad = lane >> 4;
    char* ckw = ck_all + w * CKB;

    const int i0  = (blockIdx.x * WPB + w) * TIW;   // wave's 16 i-rows
    const int j00 = blockIdx.y * KSTRIP;            // wave's j strip

    // cooc staging assignment: 4 lanes per i-row, 48B units (4 j-triples)
    const int ci = lane >> 2;   // 0..15 row within tile
    const int cq = lane & 3;
    const float* crow = cooc + ((size_t)(i0 + ci) * V + j00) * 3 + cq * 12;

    f32x4 acc[4][3] = {};        // [b-subtile][kk]
    float4 bufA[2][6], bufB[2][6];  // double-buffered cooc chunk, 2 halves each

// half h of chunk c: lanes' units _t = 2h, 2h+1
#define ISSUE_HALF(buf, c, h)                                                 \
    do {                                                                      \
        const float* _p = crow + (size_t)(c) * (JC * 3) + (h) * 96;           \
        _Pragma("unroll")                                                     \
        for (int _t = 0; _t < 2; ++_t) {                                      \
            const float* _q = _p + _t * 48;                                   \
            buf[h][_t * 3 + 0] = *(const float4*)(_q);                        \
            buf[h][_t * 3 + 1] = *(const float4*)(_q + 4);                    \
            buf[h][_t * 3 + 2] = *(const float4*)(_q + 8);                    \
        }                                                                     \
    } while (0)

// LDS layout: row = kk*16 + i (128 B each); 16B granule g of row i stored at
// (g ^ (i&7)) -> conflict-floor for both b64 writes and b128 fragment reads.
#define CONVERT_STORE_HALF(buf, h)                                            \
    do {                                                                      \
        _Pragma("unroll")                                                     \
        for (int _t = 0; _t < 2; ++_t) {                                      \
            const int _u = cq + 4 * ((h) * 2 + _t);  /* unit = 4 j-triples */ \
            const int _g = _u >> 1, _h2 = _u & 1;                             \
            const float4 _x = buf[h][_t * 3], _y = buf[h][_t * 3 + 1],        \
                         _z = buf[h][_t * 3 + 2];                             \
            const float _fl[12] = {_x.x, _x.y, _x.z, _x.w, _y.x, _y.y,        \
                                   _y.z, _y.w, _z.x, _z.y, _z.z, _z.w};       \
            _Pragma("unroll")                                                 \
            for (int _kk = 0; _kk < 3; ++_kk) {                               \
                uint2 _pk;                                                    \
                _pk.x = f2bf2(_fl[0 + _kk], _fl[3 + _kk]);                    \
                _pk.y = f2bf2(_fl[6 + _kk], _fl[9 + _kk]);                    \
                *(uint2*)(ckw + (_kk * TIW + ci) * 128 +                      \
                          ((_g ^ (ci & 7)) << 4) + (_h2 << 3)) = _pk;         \
            }                                                                 \
        }                                                                     \
    } while (0)

#define MFMA_PHASE(c)                                                         \
    do {                                                                      \
        bf16x8 _bf[2][3];                                                     \
        _Pragma("unroll")                                                     \
        for (int _s = 0; _s < 2; ++_s)                                        \
            _Pragma("unroll")                                                 \
            for (int _kk = 0; _kk < 3; ++_kk)                                 \
                _bf[_s][_kk] = *(const bf16x8*)(ckw + (_kk * TIW + il) * 128 +\
                    ((((_s << 2) | quad) ^ (il & 7)) << 4));                  \
        const float* _ab = arg + j00 + (size_t)(c) * JC + quad * 8;           \
        _Pragma("unroll")                                                     \
        for (int _bs = 0; _bs < 4; ++_bs) {                                   \
            _Pragma("unroll")                                                 \
            for (int _s = 0; _s < 2; ++_s) {                                  \
                const float* _ap = _ab + (size_t)(_bs * 16 + il) * VP2 + _s * 32; \
                float2 _a0 = *(const float2*)(_ap);                           \
                float2 _a1 = *(const float2*)(_ap + 2);                       \
                float2 _a2 = *(const float2*)(_ap + 4);                       \
                float2 _a3 = *(const float2*)(_ap + 6);                       \
                uint4 _pk4 = {f2bf2(_a0.x, _a0.y), f2bf2(_a1.x, _a1.y),       \
                              f2bf2(_a2.x, _a2.y), f2bf2(_a3.x, _a3.y)};      \
                bf16x8 _af = __builtin_bit_cast(bf16x8, _pk4);                \
                _Pragma("unroll")                                             \
                for (int _kk = 0; _kk < 3; ++_kk)                             \
                    acc[_bs][_kk] = __builtin_amdgcn_mfma_f32_16x16x32_bf16(  \
                        _af, _bf[_s][_kk], acc[_bs][_kk], 0, 0, 0);           \
            }                                                                 \
        }                                                                     \
    } while (0)

    ISSUE_HALF(bufA, 0, 0);
    ISSUE_HALF(bufA, 0, 1);
    #pragma unroll 1
    for (int c = 0; c < NCHUNK; c += 2) {
        ISSUE_HALF(bufB, c + 1, 0);   // prefetch in flight across convert+MFMA
        ISSUE_HALF(bufB, c + 1, 1);
        CONVERT_STORE_HALF(bufA, 0);
        CONVERT_STORE_HALF(bufA, 1);
        MFMA_PHASE(c);
        if (c + 2 < NCHUNK) {
            ISSUE_HALF(bufA, c + 2, 0);
            ISSUE_HALF(bufA, c + 2, 1);
        }
        CONVERT_STORE_HALF(bufB, 0);
        CONVERT_STORE_HALF(bufB, 1);
        MFMA_PHASE(c + 1);
    }

    // ---- epilogue: out[b,kk] += sum_i f[b,i] * P[b,i,kk]
    // D layout: col(=i) = il, row(=b_local) = quad*4 + r
    float fv[4][4];
    #pragma unroll
    for (int bs = 0; bs < 4; ++bs)
        #pragma unroll
        for (int r = 0; r < 4; ++r)
            fv[bs][r] = func[(size_t)(bs * 16 + quad * 4 + r) * VP2 + i0 + il];

    #pragma unroll
    for (int bs = 0; bs < 4; ++bs)
        #pragma unroll
        for (int kk = 0; kk < 3; ++kk)
            #pragma unroll
            for (int r = 0; r < 4; ++r) {
                float v = fv[bs][r] * acc[bs][kk][r];
                v += __shfl_xor(v, 1);
                v += __shfl_xor(v, 2);
                v += __shfl_xor(v, 4);
                v += __shfl_xor(v, 8);
                if (il == 0) red[w][bs * 16 + quad * 4 + r][kk] = v;
            }

    __syncthreads();  // only barrier in the kernel
    if (tid < B * 3) {
        const int b = tid / 3, kk = tid % 3;
        float v = red[0][b][kk] + red[1][b][kk] + red[2][b][kk] + red[3][b][kk];
        atomicAdd(&out[b * 3 + kk], v);
    }

#undef ISSUE_HALF
#undef CONVERT_STORE_HALF
#undef MFMA_PHASE
}

extern "C" void kernel_launch(void* const* d_in, const int* in_sizes, int n_in,
                              void* d_out, int out_size, void* d_ws, size_t ws_size,
                              hipStream_t stream) {
    const float* func = (const float*)d_in[0];
    const float* arg  = (const float*)d_in[1];
    const float* cooc = (const float*)d_in[2];
    float* out = (float*)d_out;

    // d_out is re-poisoned before every launch: write masks first, then accumulate.
    hipLaunchKernelGGL(mask_kernel, dim3(1), dim3(64), 0, stream, func, out);
    hipLaunchKernelGGL(cooc_kernel, dim3(V / (TIW * WPB), NSJ), dim3(256), 0, stream,
                       func, arg, cooc, out);
}